// Round 3
// baseline (364.199 us; speedup 1.0000x reference)
//
#include <hip/hip_runtime.h>

// Chain of 9 Linear layers, no activation => collapse to one affine map.
// dims: 784 -> 69 -> 31 -> 10 -> ... -> 10
//
// R9: FULL FUSION — one kernel. Each of 512 blocks redundantly:
//   (a) computes the collapse chain S8 = W8*...*W1 [10,69] in its own LDS
//       (~2us, all blocks in parallel; weights are L2-hits after first touch),
//   (b) folds Wt[o][j] = sum_u S8[o][u]*W0[u][j] DIRECTLY into its wlds LDS
//       buffer, j = threadIdx (+512): coalesced W0 reads, 216KB/block from
//       L2 (111MB aggregate ~ 3us), S8 read as wave-uniform LDS broadcasts,
//   (c) computes beff into LDS,
//   then one barrier and the unchanged R8 main loop. Kills the prep launch,
//   the graph serialization gap, and the Wt2/beff global round-trip
//   (workspace now unused). First x loads hoisted to the top of the kernel
//   so the HBM stream gets a head start under the prep compute.
//   R8 post-mortem: main loop is already ~HBM-floor (R8's LDS-halving
//   bought only -0.85us) -> remaining controllable time was prep+gap.
//
// MAIN (R8): 2 rows/lane. s = t&7 owns j = jb*32+s*4; rows (t>>3), +64.
//   x loads coalesced (8 rows x 128B whole lines per instr, x2 row sets).
//   Weights in LDS, padded 11*float4 per j-quad: start bank quad (3s+o)&7
//   -> all 8 addr groups disjoint, 8-way broadcast: conflict-free.
//   Tail 784=24*32+16: weight j4 196..199 zeroed, x addr clamped to 780.
//   3-step shfl_xor over the 8-lane row group; lanes s<5 write float2/row.
//   LDS 52.3KB -> 2 blocks/CU (grid 512 = exactly 2/CU), 16 waves/CU.
//
// Wt (wlds) layout: [200 j-quads][11 float4]; entry (j4, o<10) =
//   {W[o][j4*4+k]}_{k=0..3}; o==10 and j4 in [196,200) are zero padding.

__global__ __launch_bounds__(512, 4) void fused_main(
    const float* __restrict__ x,
    const float* __restrict__ W0, const float* __restrict__ b0,
    const float* __restrict__ W1, const float* __restrict__ b1,
    const float* __restrict__ W2, const float* __restrict__ b2,
    const float* __restrict__ W3, const float* __restrict__ b3,
    const float* __restrict__ W4, const float* __restrict__ b4,
    const float* __restrict__ W5, const float* __restrict__ b5,
    const float* __restrict__ W6, const float* __restrict__ b6,
    const float* __restrict__ W7, const float* __restrict__ b7,
    const float* __restrict__ W8, const float* __restrict__ b8,
    float* __restrict__ out)
{
    __shared__ float4 wlds[2200];            // 35.2 KB folded weights
    __shared__ float Sa[31 * 69], Sb[31 * 69];  // 16.7 KB chain buffers
    __shared__ float da[31], db[31], be[10];

    const int t = threadIdx.x;
    const int sseg = t & 7;                  // j-segment within row group
    const long row0 = (long)blockIdx.x * 128 + (t >> 3);   // 2nd row = +64
    const float* xr0 = x + row0 * 784;
    const float* xr1 = xr0 + (long)64 * 784;

    // issue first x loads NOW: HBM streams under the prep compute
    float4 xv0 = *(const float4*)(xr0 + sseg * 4);
    float4 xv1 = *(const float4*)(xr1 + sseg * 4);

    // zero wlds (padding entries o==10 and j>=784 must stay 0);
    // the write is >=2 barriers before the fold writes -> no extra sync
    for (int i = t; i < 2200; i += 512) wlds[i] = make_float4(0.f, 0.f, 0.f, 0.f);

    // ---- collapse chain (identical FP order to R6/R7/R8) ----
    for (int i = t; i < 31 * 69; i += 512) Sa[i] = W1[i];
    for (int i = t; i < 31; i += 512) da[i] = b1[i];
    __syncthreads();

    for (int i = t; i < 10 * 69; i += 512) {
        int o = i / 69, c = i - o * 69;
        float v = 0.f;
        for (int k = 0; k < 31; k++) v += W2[o * 31 + k] * Sa[k * 69 + c];
        Sb[i] = v;
    }
    for (int i = t; i < 10; i += 512) {
        float v = b2[i];
        for (int k = 0; k < 31; k++) v += W2[i * 31 + k] * da[k];
        db[i] = v;
    }
    __syncthreads();

    const float* Wk[6] = { W3, W4, W5, W6, W7, W8 };
    const float* bk[6] = { b3, b4, b5, b6, b7, b8 };
    int src = 1;  // runtime ternaries: gfx950 rejects arrays of LDS pointers
    for (int st = 0; st < 6; st++) {
        const float* W = Wk[st];
        const float* bb = bk[st];
        float* S  = src ? Sb : Sa;
        float* D  = src ? Sa : Sb;
        float* dd = src ? db : da;
        float* dn = src ? da : db;
        for (int i = t; i < 10 * 69; i += 512) {
            int o = i / 69, c = i - o * 69;
            float v = 0.f;
            for (int k = 0; k < 10; k++) v += W[o * 10 + k] * S[k * 69 + c];
            D[i] = v;
        }
        for (int i = t; i < 10; i += 512) {
            float v = bb[i];
            for (int k = 0; k < 10; k++) v += W[i * 10 + k] * dd[k];
            dn[i] = v;
        }
        __syncthreads();
        src ^= 1;
    }

    float* S  = src ? Sb : Sa;   // src back to 1 after 6 flips -> Sb
    float* dd = src ? db : da;

    // ---- beff (every block, redundant; same FP order) ----
    for (int i = t; i < 10; i += 512) {
        float v = dd[i];
        for (int k = 0; k < 69; k++) v += S[i * 69 + k] * b0[k];
        be[i] = v;
    }

    // ---- fold W0 into wlds: thread t owns j = t (and t+512 if t<272) ----
    {
        float a0[10], a1[10];
#pragma unroll
        for (int o = 0; o < 10; o++) { a0[o] = 0.f; a1[o] = 0.f; }
        const bool two = (t < 272);          // j2 = t+512 < 784
        for (int u = 0; u < 69; u++) {
            float s8v[10];
#pragma unroll
            for (int o = 0; o < 10; o++) s8v[o] = S[o * 69 + u];  // broadcast
            float w0 = W0[u * 784 + t];      // coalesced, L2-hit
#pragma unroll
            for (int o = 0; o < 10; o++) a0[o] = fmaf(s8v[o], w0, a0[o]);
            if (two) {
                float w1 = W0[u * 784 + t + 512];
#pragma unroll
                for (int o = 0; o < 10; o++) a1[o] = fmaf(s8v[o], w1, a1[o]);
            }
        }
        float* wf = (float*)wlds;
        const int j = t;
#pragma unroll
        for (int o = 0; o < 10; o++)
            wf[(j >> 2) * 44 + o * 4 + (j & 3)] = a0[o];
        if (two) {
            const int j2 = t + 512;
#pragma unroll
            for (int o = 0; o < 10; o++)
                wf[(j2 >> 2) * 44 + o * 4 + (j2 & 3)] = a1[o];
        }
    }
    __syncthreads();   // wlds + be ready

    // ---- main loop (unchanged R8) ----
    float acc0[10], acc1[10];
#pragma unroll
    for (int o = 0; o < 10; o++) { acc0[o] = 0.f; acc1[o] = 0.f; }

    for (int jb = 0; jb < 25; jb++) {
        float4 xc0 = xv0, xc1 = xv1;
        if (jb < 24) {
            int jn = (jb + 1) * 32 + sseg * 4;
            jn = jn > 780 ? 780 : jn;        // clamp: tail cols have zero W
            xv0 = *(const float4*)(xr0 + jn);
            xv1 = *(const float4*)(xr1 + jn);
        }
        const float4* wrow = &wlds[(jb * 8 + sseg) * 11];
#pragma unroll
        for (int o = 0; o < 10; o++) {
            float4 wv = wrow[o];
            acc0[o] = fmaf(xc0.x, wv.x, acc0[o]);
            acc0[o] = fmaf(xc0.y, wv.y, acc0[o]);
            acc0[o] = fmaf(xc0.z, wv.z, acc0[o]);
            acc0[o] = fmaf(xc0.w, wv.w, acc0[o]);
            acc1[o] = fmaf(xc1.x, wv.x, acc1[o]);
            acc1[o] = fmaf(xc1.y, wv.y, acc1[o]);
            acc1[o] = fmaf(xc1.z, wv.z, acc1[o]);
            acc1[o] = fmaf(xc1.w, wv.w, acc1[o]);
        }
    }

    // butterfly sum over the 8 lanes sharing each row (bits 0..2 of lane id)
#pragma unroll
    for (int m = 1; m < 8; m <<= 1)
#pragma unroll
        for (int o = 0; o < 10; o++) {
            acc0[o] += __shfl_xor(acc0[o], m, 64);
            acc1[o] += __shfl_xor(acc1[o], m, 64);
        }

    // lanes sseg<5 write float2 per row (out + row*10 is 8B-aligned)
    if (sseg < 5) {
        float lo0 = 0.f, hi0 = 0.f, lo1 = 0.f, hi1 = 0.f;
#pragma unroll
        for (int o = 0; o < 5; o++) {
            if (sseg == o) {                 // cndmask chain
                lo0 = acc0[2 * o]; hi0 = acc0[2 * o + 1];
                lo1 = acc1[2 * o]; hi1 = acc1[2 * o + 1];
            }
        }
        float be0 = be[sseg * 2], be1 = be[sseg * 2 + 1];
        *(float2*)(out + row0 * 10 + sseg * 2) = make_float2(lo0 + be0, hi0 + be1);
        *(float2*)(out + (row0 + 64) * 10 + sseg * 2) = make_float2(lo1 + be0, hi1 + be1);
    }
}

extern "C" void kernel_launch(void* const* d_in, const int* in_sizes, int n_in,
                              void* d_out, int out_size, void* d_ws, size_t ws_size,
                              hipStream_t stream) {
    const float* x  = (const float*)d_in[0];
    const float* W0 = (const float*)d_in[1];
    const float* b0 = (const float*)d_in[2];
    const float* W1 = (const float*)d_in[3];
    const float* b1 = (const float*)d_in[4];
    const float* W2 = (const float*)d_in[5];
    const float* b2 = (const float*)d_in[6];
    const float* W3 = (const float*)d_in[7];
    const float* b3 = (const float*)d_in[8];
    const float* W4 = (const float*)d_in[9];
    const float* b4 = (const float*)d_in[10];
    const float* W5 = (const float*)d_in[11];
    const float* b5 = (const float*)d_in[12];
    const float* W6 = (const float*)d_in[13];
    const float* b6 = (const float*)d_in[14];
    const float* W7 = (const float*)d_in[15];
    const float* b7 = (const float*)d_in[16];
    const float* W8 = (const float*)d_in[17];
    const float* b8 = (const float*)d_in[18];
    (void)d_ws; (void)ws_size;               // workspace no longer used

    float* out = (float*)d_out;
    const int B = in_sizes[0] / 784;         // 65536

    fused_main<<<B / 128, 512, 0, stream>>>(x,
        W0, b0, W1, b1, W2, b2, W3, b3, W4, b4,
        W5, b5, W6, b6, W7, b7, W8, b8, out);
}